// Round 10
// baseline (2002.844 us; speedup 1.0000x reference)
//
#include <hip/hip_runtime.h>

#define FDIM 128
#define PH_SHIFT 13          // phase = col >> 13 (8192 rows = 2MB bf16 X-slice / XCD L2)
#define NPH 13
#define G 16                 // rows per wave (16 adjacent rows, 8 half-wave pairs)

typedef __attribute__((ext_vector_type(8))) short short8v;   // 8 bf16
typedef __attribute__((ext_vector_type(4))) float f32x4;

// ---------- bf16 helpers (manual, RNE) ----------
__device__ __forceinline__ uint16_t f2bf(float f) {
    uint32_t u = __float_as_uint(f);
    uint32_t r = (u + 0x7fffu + ((u >> 16) & 1u)) >> 16;
    return (uint16_t)r;
}
__device__ __forceinline__ uint32_t pack_bf16(float a, float b) {
    return (uint32_t)f2bf(a) | ((uint32_t)f2bf(b) << 16);
}
__device__ __forceinline__ float bflo(uint32_t u) { return __uint_as_float(u << 16); }
__device__ __forceinline__ float bfhi(uint32_t u) { return __uint_as_float(u & 0xffff0000u); }

// ---------------------------------------------------------------------------
// row_ptr[i] = lower_bound(rows, i). rows sorted.
// ---------------------------------------------------------------------------
__global__ __launch_bounds__(256) void build_row_ptr_k(const int* __restrict__ rows,
                                                       int E, int N,
                                                       int* __restrict__ rp) {
    int i = blockIdx.x * 256 + threadIdx.x;
    if (i > N) return;
    int lo = 0, hi = E;
    while (lo < hi) {
        int mid = (lo + hi) >> 1;
        if (rows[mid] < i) lo = mid + 1; else hi = mid;
    }
    rp[i] = lo;
}

// ---------------------------------------------------------------------------
// Wt[n][k] = bf16(W[k][n]), 128x128.
// ---------------------------------------------------------------------------
__global__ __launch_bounds__(256) void transpose_w_k(const float* __restrict__ W,
                                                     uint16_t* __restrict__ Wt) {
    int idx = blockIdx.x * 256 + threadIdx.x;   // 0..16383
    int k = idx >> 7, n = idx & 127;
    Wt[n * FDIM + k] = f2bf(W[k * FDIM + n]);
}

__global__ __launch_bounds__(256) void zero_k(int* __restrict__ a, int n) {
    int i = blockIdx.x * 256 + threadIdx.x;
    if (i < n) a[i] = 0;
}

// ---------------------------------------------------------------------------
// reorder_k: per-row ballot counting sort by phase. Writes edge2[i] =
// (FULL col, f32 val bits) — order-robust: a misplaced edge only costs
// locality. Also writes seg[r][p] (absolute edge index of phase-p segment
// start; seg[r][13] = row end). Union over p of [seg[p], seg[p+1]) =
// [rp[r], rp[r+1]) by cumulative construction.
// ---------------------------------------------------------------------------
__global__ __launch_bounds__(256) void reorder_k(const int* __restrict__ rp,
                                                 const int* __restrict__ cols,
                                                 const float* __restrict__ vals,
                                                 int2* __restrict__ edge2,
                                                 int* __restrict__ seg, int N) {
    int r    = (blockIdx.x * 256 + threadIdx.x) >> 6;
    int lane = threadIdx.x & 63;
    if (r >= N) return;
    int s = __builtin_amdgcn_readfirstlane(rp[r]);
    int e = __builtin_amdgcn_readfirstlane(rp[r + 1]);
    int deg = e - s;

    if (deg <= 64) {
        bool valid = lane < deg;
        int   c = valid ? cols[s + lane] : 0x7fffffff;
        float v = valid ? vals[s + lane] : 0.f;
        int  ph = c >> PH_SHIFT;               // invalid lanes: huge, never matches
        int base = 0;
        int myseg = e;                         // lane 13 default: row end
        for (int p = 0; p < NPH; ++p) {
            if (lane == p) myseg = s + base;
            unsigned long long m = __ballot(ph == p);
            int pref = __popcll(m & ((1ull << lane) - 1ull));
            if (ph == p) edge2[s + base + pref] = make_int2(c, __float_as_int(v));
            base += __popcll(m);
        }
        if (lane < 14) seg[(size_t)r * 14 + lane] = myseg;
    } else if (lane == 0) {
        // rare fallback (degree beyond 64)
        int b = 0;
        for (int p = 0; p < NPH; ++p) {
            seg[(size_t)r * 14 + p] = s + b;
            for (int i = s; i < e; ++i) {
                int c = cols[i];
                if ((c >> PH_SHIFT) == p) {
                    edge2[s + b] = make_int2(c, __float_as_int(vals[i]));
                    ++b;
                }
            }
        }
        seg[(size_t)r * 14 + 13] = e;
    }
}

// ---------------------------------------------------------------------------
// GEMM: C = A @ W via bf16 MFMA 16x16x32 (validated round 3).
// ---------------------------------------------------------------------------
template <int ABF>
__global__ __launch_bounds__(256) void gemm_mfma_k(const void* __restrict__ A_,
                                                   const uint16_t* __restrict__ Wt,
                                                   uint16_t* __restrict__ C, int M) {
    const int t = threadIdx.x;
    const int w = t >> 6;
    const int l = t & 63;
    const int row0 = blockIdx.x * 128 + w * 32;

    f32x4 acc[2][8];
#pragma unroll
    for (int mf = 0; mf < 2; ++mf)
#pragma unroll
        for (int nf = 0; nf < 8; ++nf) acc[mf][nf] = (f32x4)0.f;

    const int lr = l & 15;
    const int kg = l >> 4;

#pragma unroll
    for (int ks = 0; ks < 4; ++ks) {
        const int k0 = ks * 32 + kg * 8;
        short8v a[2];
#pragma unroll
        for (int mf = 0; mf < 2; ++mf) {
            int r = row0 + mf * 16 + lr;
            if (r >= M) r = M - 1;      // safe clamp; stores guarded
            if constexpr (ABF) {
                a[mf] = *(const short8v*)((const uint16_t*)A_ + (size_t)r * FDIM + k0);
            } else {
                const float* ap = (const float*)A_ + (size_t)r * FDIM + k0;
                float4 f0 = *(const float4*)(ap);
                float4 f1 = *(const float4*)(ap + 4);
                uint32_t p0 = pack_bf16(f0.x, f0.y), p1 = pack_bf16(f0.z, f0.w);
                uint32_t p2 = pack_bf16(f1.x, f1.y), p3 = pack_bf16(f1.z, f1.w);
                uint4 u = make_uint4(p0, p1, p2, p3);
                a[mf] = *(short8v*)&u;
            }
        }
#pragma unroll
        for (int nf = 0; nf < 8; ++nf) {
            short8v b = *(const short8v*)(Wt + (size_t)(nf * 16 + lr) * FDIM + k0);
            acc[0][nf] = __builtin_amdgcn_mfma_f32_16x16x32_bf16(a[0], b, acc[0][nf], 0, 0, 0);
            acc[1][nf] = __builtin_amdgcn_mfma_f32_16x16x32_bf16(a[1], b, acc[1][nf], 0, 0, 0);
        }
    }

    const int colpar = l & 1;
#pragma unroll
    for (int mf = 0; mf < 2; ++mf) {
#pragma unroll
        for (int nf = 0; nf < 8; ++nf) {
            int col = nf * 16 + lr;
#pragma unroll
            for (int j = 0; j < 4; ++j) {
                float v = acc[mf][nf][j];
                float pv = __shfl_xor(v, 1);
                int row = row0 + mf * 16 + kg * 4 + j;
                if (!colpar && row < M) {
                    *(uint32_t*)(C + (size_t)row * FDIM + col) = pack_bf16(v, pv);
                }
            }
        }
    }
}

// ---------------------------------------------------------------------------
// SPMM v5: phase-major outer loop x R9 consumer. Wave owns 16 adjacent rows
// (8 half-wave pairs, static acc indices). 6250 waves ~ one residency
// generation -> all waves sweep phase p together; active X slice = 2MB,
// L2-resident per XCD. Per phase: one coalesced seg load (lanes 0..31),
// then per pair the predicated 2-cursor loop: 1 edge2 broadcast load +
// 1 uint2 gather + 4 FMA per edge per half.
// ---------------------------------------------------------------------------
template <int RELU, int OBF>
__global__ __launch_bounds__(256) void spmm5_k(const int* __restrict__ seg,
                                               const int2* __restrict__ edge2,
                                               const uint32_t* __restrict__ X, // bf16x2 rows
                                               const float* __restrict__ bias,
                                               void* __restrict__ out, int N) {
    const int wid  = (blockIdx.x * 256 + threadIdx.x) >> 6;
    const int lane = threadIdx.x & 63;
    const int half = lane >> 5;
    const int f    = lane & 31;
    const int r0   = wid * G;
    if (r0 >= N) return;

    float a0[G / 2], a1[G / 2], a2[G / 2], a3[G / 2];
#pragma unroll
    for (int jp = 0; jp < G / 2; ++jp) { a0[jp] = a1[jp] = a2[jp] = a3[jp] = 0.f; }

    // lane 2j+b (j<16) reads seg[r0+j][p+b] each phase
    const int bj = (lane >> 1) & (G - 1);
    const int bb = lane & 1;
    const int* segrow = seg + (size_t)(r0 + bj) * 14 + bb;

    for (int p = 0; p < NPH; ++p) {
        int sg = segrow[p];
#pragma unroll
        for (int jp = 0; jp < G / 2; ++jp) {
            int iA = __shfl(sg, 4 * jp);
            int eA = __shfl(sg, 4 * jp + 1);
            int iB = __shfl(sg, 4 * jp + 2);
            int eB = __shfl(sg, 4 * jp + 3);
            if (iA < eA || iB < eB) {
                float b0 = a0[jp], b1 = a1[jp], b2 = a2[jp], b3 = a3[jp];
                do {
                    int  i0 = half ? iB : iA;
                    int  ee = half ? eB : eA;
                    bool q  = i0 < ee;
                    int2 ev = edge2[q ? i0 : 0];
                    float v = q ? __int_as_float(ev.y) : 0.f;
                    uint2 u = *(const uint2*)(X + (size_t)ev.x * 64 + 2 * f);
                    b0 = fmaf(v, bflo(u.x), b0); b1 = fmaf(v, bfhi(u.x), b1);
                    b2 = fmaf(v, bflo(u.y), b2); b3 = fmaf(v, bfhi(u.y), b3);
                    iA = iA < eA ? iA + 1 : iA;
                    iB = iB < eB ? iB + 1 : iB;
                } while (iA < eA || iB < eB);
                a0[jp] = b0; a1[jp] = b1; a2[jp] = b2; a3[jp] = b3;
            }
        }
    }

    float4 bs = *(const float4*)(bias + 4 * f);
#pragma unroll
    for (int jp = 0; jp < G / 2; ++jp) {
        int r = r0 + 2 * jp + half;
        if (r >= N) continue;
        float o0 = a0[jp] + bs.x, o1 = a1[jp] + bs.y;
        float o2 = a2[jp] + bs.z, o3 = a3[jp] + bs.w;
        if (RELU) {
            o0 = fmaxf(o0, 0.f); o1 = fmaxf(o1, 0.f);
            o2 = fmaxf(o2, 0.f); o3 = fmaxf(o3, 0.f);
        }
        if constexpr (OBF) {
            *(uint2*)((uint32_t*)out + (size_t)r * 64 + 2 * f) =
                make_uint2(pack_bf16(o0, o1), pack_bf16(o2, o3));
        } else {
            *(float4*)((float*)out + (size_t)r * FDIM + 4 * f) =
                make_float4(o0, o1, o2, o3);
        }
    }
}

// ---------------------------------------------------------------------------
extern "C" void kernel_launch(void* const* d_in, const int* in_sizes, int n_in,
                              void* d_out, int out_size, void* d_ws, size_t ws_size,
                              hipStream_t stream) {
    const float* features = (const float*)d_in[0];
    const int*   adj_rows = (const int*)d_in[1];
    const int*   adj_cols = (const int*)d_in[2];
    const float* adj_vals = (const float*)d_in[3];
    const float* W1       = (const float*)d_in[4];
    const float* b1       = (const float*)d_in[5];
    const float* W2       = (const float*)d_in[6];
    const float* b2       = (const float*)d_in[7];

    const int N = in_sizes[0] / FDIM;    // 100000
    const int E = in_sizes[1];           // 3200000
    float* out = (float*)d_out;
    const int NPAD = ((N + G - 1) / G) * G;   // 100000 (exact multiple)

    // ws layout (~83 MB; >=103 MB proven available in round 1)
    char* ws = (char*)d_ws;
    int*      rp    = (int*)ws;                               // (N+1)*4
    size_t    rp_b  = (((size_t)(N + 1) * 4) + 255) & ~(size_t)255;
    int2*     edge2 = (int2*)(ws + rp_b);                     // E*8 = 25.6 MB
    size_t    e2_b  = (((size_t)E * 8) + 255) & ~(size_t)255;
    int*      seg   = (int*)((char*)edge2 + e2_b);            // NPAD*14*4 = 5.6 MB
    size_t    sg_b  = (((size_t)NPAD * 14 * 4) + 255) & ~(size_t)255;
    uint16_t* XWb   = (uint16_t*)((char*)seg + sg_b);         // N*128 bf16 = 25.6 MB
    uint16_t* Hb    = XWb + (size_t)N * FDIM;                 // N*128 bf16 = 25.6 MB
    uint16_t* W1t   = Hb + (size_t)N * FDIM;                  // 32 KB
    uint16_t* W2t   = W1t + FDIM * FDIM;                      // 32 KB

    const int nblk_gemm = (N + 127) / 128;
    const int nwave     = NPAD / G;                           // 6250
    const int nblk_spmm = (nwave + 3) / 4;                    // 1563 blocks

    // --- preprocessing ---
    build_row_ptr_k<<<(N + 256) / 256, 256, 0, stream>>>(adj_rows, E, N, rp);
    transpose_w_k<<<64, 256, 0, stream>>>(W1, W1t);
    transpose_w_k<<<64, 256, 0, stream>>>(W2, W2t);
    zero_k<<<(NPAD * 14 + 255) / 256, 256, 0, stream>>>(seg, NPAD * 14);
    reorder_k<<<(int)(((size_t)N * 64 + 255) / 256), 256, 0, stream>>>(
        rp, adj_cols, adj_vals, edge2, seg, N);
    // --- layer 1 ---
    gemm_mfma_k<0><<<nblk_gemm, 256, 0, stream>>>((const void*)features, W1t, XWb, N);
    spmm5_k<1, 1><<<nblk_spmm, 256, 0, stream>>>(seg, edge2, (const uint32_t*)XWb,
                                                 b1, (void*)Hb, N);
    // --- layer 2 ---
    gemm_mfma_k<1><<<nblk_gemm, 256, 0, stream>>>((const void*)Hb, W2t, XWb, N);
    spmm5_k<0, 0><<<nblk_spmm, 256, 0, stream>>>(seg, edge2, (const uint32_t*)XWb,
                                                 b2, (void*)out, N);
}